// Round 5
// baseline (342.501 us; speedup 1.0000x reference)
//
#include <hip/hip_runtime.h>

#define D_IN 512
#define D_OUT 256
#define BM 128
#define BN 128
#define BK 32
#define LDK 40   // padded LDS row stride (elems): 80 B, 16B-aligned rows, 2-way bank alias

#define HIST_BLOCKS 1563          // ceil(800000 / 512)
#define GEMM_MTILES 391           // ceil(50000 / 128)
#define GEMM_BLOCKS (GEMM_MTILES * 2)

typedef short short8 __attribute__((ext_vector_type(8)));
typedef float floatx4 __attribute__((ext_vector_type(4)));

static __device__ __forceinline__ unsigned short f2bf(float f) {
    unsigned u = __float_as_uint(f);
    u += 0x7FFF + ((u >> 16) & 1);
    return (unsigned short)(u >> 16);
}
static __device__ __forceinline__ float bf2f(unsigned short h) {
    return __uint_as_float((unsigned)h << 16);
}

// ---------------- prep: convert W + zero cnt (one dispatch) ----------------
// blocks [0,512): Wt[n][k] = bf16(W[k][n]);  blocks [512,561): cnt = 0
__global__ __launch_bounds__(256) void prep(const float* __restrict__ W,
                                            unsigned short* __restrict__ Wt,
                                            int* __restrict__ cnt, int M) {
    int b = blockIdx.x;
    if (b < 512) {
        int t = b * 256 + threadIdx.x;
        int n = t >> 9;
        int k = t & 511;
        Wt[t] = f2bf(W[(size_t)k * D_OUT + n]);
    } else {
        int i = (b - 512) * 256 + threadIdx.x;
        if (i < M) cnt[i] = 0;
    }
}

// ---------------- fused: gemm (bf16 MFMA) + edge-row histogram ----------------
// blocks [0, HIST_BLOCKS): histogram (512 edges/block)
// blocks [HIST_BLOCKS, HIST_BLOCKS+GEMM_BLOCKS): gemm tiles
__global__ __launch_bounds__(512) void gemm_hist(const float* __restrict__ A,
                                                 const unsigned short* __restrict__ Wt,
                                                 unsigned short* __restrict__ S,
                                                 const int* __restrict__ rows,
                                                 int* __restrict__ cnt, int M, int E) {
    if (blockIdx.x < HIST_BLOCKS) {
        int e = blockIdx.x * 512 + threadIdx.x;
        if (e < E) atomicAdd(&cnt[rows[e]], 1);
        return;
    }
    const int gb = blockIdx.x - HIST_BLOCKS;
    const int bm = (gb >> 1) * BM;
    const int bn = (gb & 1) * BN;

    __shared__ unsigned short As[BM * LDK];
    __shared__ unsigned short Bs[BN * LDK];
    const int tid  = threadIdx.x;
    const int lane = tid & 63;
    const int wave = tid >> 6;
    const int wm   = (wave >> 2) * 64;
    const int wn   = (wave & 3) * 32;
    const int l15  = lane & 15;
    const int quad = lane >> 4;

    const float* aptr[2];
    const unsigned short* bptr[2];
    int aoff[2], boff[2];
    bool aval[2];
#pragma unroll
    for (int i = 0; i < 2; ++i) {
        int item = tid + i * 512;
        int m  = item >> 3;
        int k4 = (item & 7) * 4;
        int gm = bm + m;
        aval[i] = gm < M;
        aptr[i] = A + (size_t)(aval[i] ? gm : 0) * D_IN + k4;
        aoff[i] = m * LDK + k4;
        bptr[i] = Wt + (size_t)(bn + m) * D_IN + k4;
        boff[i] = m * LDK + k4;
    }

    float4  aR[2];
    ushort4 bR[2];
#pragma unroll
    for (int i = 0; i < 2; ++i) {
        aR[i] = aval[i] ? *(const float4*)(aptr[i]) : make_float4(0.f, 0.f, 0.f, 0.f);
        bR[i] = *(const ushort4*)(bptr[i]);
    }

    floatx4 acc[4][2] = {};

    for (int k0 = 0; k0 < D_IN; k0 += BK) {
#pragma unroll
        for (int i = 0; i < 2; ++i) {
            ushort4 b;
            b.x = f2bf(aR[i].x); b.y = f2bf(aR[i].y);
            b.z = f2bf(aR[i].z); b.w = f2bf(aR[i].w);
            *(ushort4*)(As + aoff[i]) = b;
            *(ushort4*)(Bs + boff[i]) = bR[i];
        }
        __syncthreads();

        if (k0 + BK < D_IN) {
#pragma unroll
            for (int i = 0; i < 2; ++i) {
                aR[i] = aval[i] ? *(const float4*)(aptr[i] + k0 + BK)
                                : make_float4(0.f, 0.f, 0.f, 0.f);
                bR[i] = *(const ushort4*)(bptr[i] + k0 + BK);
            }
        }

        short8 af[4], bfr[2];
#pragma unroll
        for (int i = 0; i < 4; ++i)
            af[i] = *(const short8*)(As + (wm + i * 16 + l15) * LDK + quad * 8);
#pragma unroll
        for (int j = 0; j < 2; ++j)
            bfr[j] = *(const short8*)(Bs + (wn + j * 16 + l15) * LDK + quad * 8);
#pragma unroll
        for (int i = 0; i < 4; ++i)
#pragma unroll
            for (int j = 0; j < 2; ++j)
                acc[i][j] = __builtin_amdgcn_mfma_f32_16x16x32_bf16(
                    af[i], bfr[j], acc[i][j], 0, 0, 0);
        __syncthreads();
    }

#pragma unroll
    for (int i = 0; i < 4; ++i) {
#pragma unroll
        for (int r = 0; r < 4; ++r) {
            int gm = bm + wm + i * 16 + quad * 4 + r;
            if (gm < M) {
#pragma unroll
                for (int j = 0; j < 2; ++j)
                    S[(size_t)gm * D_OUT + bn + wn + j * 16 + l15] = f2bf(acc[i][j][r]);
            }
        }
    }
}

// ---------------- scan: cnt -> ptr (exclusive), fill = ptr copy ----------------
// Single block, 1024 threads, 13 int4 chunks with serial carry.
__global__ __launch_bounds__(1024) void scan_rowptr(const int* __restrict__ cnt,
                                                    int* __restrict__ ptr,
                                                    int* __restrict__ fill, int M) {
    __shared__ int wsum[16];
    __shared__ int sh_carry;
    const int t = threadIdx.x, lane = t & 63, wave = t >> 6;
    if (t == 0) sh_carry = 0;
    __syncthreads();
    for (int base0 = 0; base0 < M; base0 += 4096) {
        int base = base0 + t * 4;
        int4 v = make_int4(0, 0, 0, 0);
        if (base + 3 < M) v = *(const int4*)(cnt + base);
        else {
            if (base + 0 < M) v.x = cnt[base + 0];
            if (base + 1 < M) v.y = cnt[base + 1];
            if (base + 2 < M) v.z = cnt[base + 2];
        }
        int s = v.x + v.y + v.z + v.w;
        int incl = s;
#pragma unroll
        for (int off = 1; off < 64; off <<= 1) {
            int x = __shfl_up(incl, off, 64);
            if (lane >= off) incl += x;
        }
        if (lane == 63) wsum[wave] = incl;
        __syncthreads();
        if (t == 0) {
            int run = sh_carry;
#pragma unroll
            for (int w = 0; w < 16; ++w) { int x = wsum[w]; wsum[w] = run; run += x; }
            sh_carry = run;
        }
        __syncthreads();
        int e0 = wsum[wave] + (incl - s);
        int e1 = e0 + v.x, e2 = e1 + v.y, e3 = e2 + v.z;
        if (base + 3 < M) {
            *(int4*)(ptr + base)  = make_int4(e0, e1, e2, e3);
            *(int4*)(fill + base) = make_int4(e0, e1, e2, e3);
        } else {
            if (base + 0 < M) { ptr[base + 0] = e0; fill[base + 0] = e0; }
            if (base + 1 < M) { ptr[base + 1] = e1; fill[base + 1] = e1; }
            if (base + 2 < M) { ptr[base + 2] = e2; fill[base + 2] = e2; }
        }
        __syncthreads();
    }
    if (t == 0) ptr[M] = sh_carry;
}

// ---------------- place edges at sorted positions ----------------
__global__ __launch_bounds__(256) void build_sorted(const float* __restrict__ vals,
                                                    const int* __restrict__ rows,
                                                    const int* __restrict__ cols,
                                                    int* __restrict__ fill,
                                                    int2* __restrict__ edges, int E) {
    int e = blockIdx.x * 256 + threadIdx.x;
    if (e >= E) return;
    int pos = atomicAdd(&fill[rows[e]], 1);
    edges[pos] = make_int2(cols[e], __float_as_int(vals[e]));
}

// ---------------- aggregate: one wave/row, 8-edge unroll ----------------
__global__ __launch_bounds__(256) void spmm_rows(const unsigned short* __restrict__ S,
                                                 const int2* __restrict__ edges,
                                                 const int* __restrict__ ptr,
                                                 const float* __restrict__ bias,
                                                 float* __restrict__ out, int M) {
    const int row = blockIdx.x * 4 + (threadIdx.x >> 6);
    if (row >= M) return;
    const int lane = threadIdx.x & 63;
    float4 a0 = ((const float4*)bias)[lane];
    float4 a1 = make_float4(0.f, 0.f, 0.f, 0.f);
    float4 a2 = make_float4(0.f, 0.f, 0.f, 0.f);
    float4 a3 = make_float4(0.f, 0.f, 0.f, 0.f);
    const int beg = ptr[row];
    const int end = ptr[row + 1];
    int j = beg;
    const int end8 = beg + ((end - beg) & ~7);
    for (; j < end8; j += 8) {
        int4 p01 = *(const int4*)(edges + j);
        int4 p23 = *(const int4*)(edges + j + 2);
        int4 p45 = *(const int4*)(edges + j + 4);
        int4 p67 = *(const int4*)(edges + j + 6);
        ushort4 s0 = ((const ushort4*)(S + (size_t)p01.x * D_OUT))[lane];
        ushort4 s1 = ((const ushort4*)(S + (size_t)p01.z * D_OUT))[lane];
        ushort4 s2 = ((const ushort4*)(S + (size_t)p23.x * D_OUT))[lane];
        ushort4 s3 = ((const ushort4*)(S + (size_t)p23.z * D_OUT))[lane];
        ushort4 s4 = ((const ushort4*)(S + (size_t)p45.x * D_OUT))[lane];
        ushort4 s5 = ((const ushort4*)(S + (size_t)p45.z * D_OUT))[lane];
        ushort4 s6 = ((const ushort4*)(S + (size_t)p67.x * D_OUT))[lane];
        ushort4 s7 = ((const ushort4*)(S + (size_t)p67.z * D_OUT))[lane];
        float v0 = __int_as_float(p01.y), v1 = __int_as_float(p01.w);
        float v2 = __int_as_float(p23.y), v3 = __int_as_float(p23.w);
        float v4 = __int_as_float(p45.y), v5 = __int_as_float(p45.w);
        float v6 = __int_as_float(p67.y), v7 = __int_as_float(p67.w);
        a0.x += v0 * bf2f(s0.x) + v4 * bf2f(s4.x);
        a0.y += v0 * bf2f(s0.y) + v4 * bf2f(s4.y);
        a0.z += v0 * bf2f(s0.z) + v4 * bf2f(s4.z);
        a0.w += v0 * bf2f(s0.w) + v4 * bf2f(s4.w);
        a1.x += v1 * bf2f(s1.x) + v5 * bf2f(s5.x);
        a1.y += v1 * bf2f(s1.y) + v5 * bf2f(s5.y);
        a1.z += v1 * bf2f(s1.z) + v5 * bf2f(s5.z);
        a1.w += v1 * bf2f(s1.w) + v5 * bf2f(s5.w);
        a2.x += v2 * bf2f(s2.x) + v6 * bf2f(s6.x);
        a2.y += v2 * bf2f(s2.y) + v6 * bf2f(s6.y);
        a2.z += v2 * bf2f(s2.z) + v6 * bf2f(s6.z);
        a2.w += v2 * bf2f(s2.w) + v6 * bf2f(s6.w);
        a3.x += v3 * bf2f(s3.x) + v7 * bf2f(s7.x);
        a3.y += v3 * bf2f(s3.y) + v7 * bf2f(s7.y);
        a3.z += v3 * bf2f(s3.z) + v7 * bf2f(s7.z);
        a3.w += v3 * bf2f(s3.w) + v7 * bf2f(s7.w);
    }
    if (j + 3 < end) {
        int4 p01 = *(const int4*)(edges + j);
        int4 p23 = *(const int4*)(edges + j + 2);
        ushort4 s0 = ((const ushort4*)(S + (size_t)p01.x * D_OUT))[lane];
        ushort4 s1 = ((const ushort4*)(S + (size_t)p01.z * D_OUT))[lane];
        ushort4 s2 = ((const ushort4*)(S + (size_t)p23.x * D_OUT))[lane];
        ushort4 s3 = ((const ushort4*)(S + (size_t)p23.z * D_OUT))[lane];
        float v0 = __int_as_float(p01.y), v1 = __int_as_float(p01.w);
        float v2 = __int_as_float(p23.y), v3 = __int_as_float(p23.w);
        a0.x += v0 * bf2f(s0.x) + v2 * bf2f(s2.x);
        a0.y += v0 * bf2f(s0.y) + v2 * bf2f(s2.y);
        a0.z += v0 * bf2f(s0.z) + v2 * bf2f(s2.z);
        a0.w += v0 * bf2f(s0.w) + v2 * bf2f(s2.w);
        a1.x += v1 * bf2f(s1.x) + v3 * bf2f(s3.x);
        a1.y += v1 * bf2f(s1.y) + v3 * bf2f(s3.y);
        a1.z += v1 * bf2f(s1.z) + v3 * bf2f(s3.z);
        a1.w += v1 * bf2f(s1.w) + v3 * bf2f(s3.w);
        j += 4;
    }
    for (; j < end; ++j) {
        int2 e = edges[j];
        float v = __int_as_float(e.y);
        ushort4 s = ((const ushort4*)(S + (size_t)e.x * D_OUT))[lane];
        a0.x += v * bf2f(s.x);
        a0.y += v * bf2f(s.y);
        a0.z += v * bf2f(s.z);
        a0.w += v * bf2f(s.w);
    }
    a0.x += a1.x + a2.x + a3.x;
    a0.y += a1.y + a2.y + a3.y;
    a0.z += a1.z + a2.z + a3.z;
    a0.w += a1.w + a2.w + a3.w;
    ((float4*)out)[(size_t)row * 64 + lane] = a0;
}

extern "C" void kernel_launch(void* const* d_in, const int* in_sizes, int n_in,
                              void* d_out, int out_size, void* d_ws, size_t ws_size,
                              hipStream_t stream) {
    const float* inputs    = (const float*)d_in[0];
    const float* weights   = (const float*)d_in[1];
    const float* bias      = (const float*)d_in[2];
    const float* edge_vals = (const float*)d_in[3];
    const int*   edge_row  = (const int*)d_in[4];
    const int*   edge_col  = (const int*)d_in[5];
    float* out = (float*)d_out;

    const int M = in_sizes[0] / D_IN;  // 50000
    const int E = in_sizes[3];         // 800000

    // Workspace:
    //   S:     M*D_OUT bf16    (25.6 MB)
    //   Wt:    D_OUT*D_IN bf16 (256 KB)
    //   edges: E int2          (6.4 MB)
    //   ptr:   M+1 ints; cnt: M ints; fill: M ints
    char* ws = (char*)d_ws;
    unsigned short* S  = (unsigned short*)ws;
    unsigned short* Wt = (unsigned short*)(ws + (size_t)M * D_OUT * 2);
    int2* edges        = (int2*)((char*)Wt + (size_t)D_OUT * D_IN * 2);
    int*  ptr          = (int*)((char*)edges + (size_t)E * 8);
    int*  cnt          = ptr + ((M + 4) & ~3);
    int*  fill         = cnt + ((M + 4) & ~3);

    // 1) convert W + zero cnt
    prep<<<512 + (M + 255) / 256, 256, 0, stream>>>(weights, Wt, cnt, M);

    // 2) gemm (bf16 MFMA) + histogram, fused
    gemm_hist<<<HIST_BLOCKS + GEMM_BLOCKS, 512, 0, stream>>>(inputs, Wt, S, edge_row,
                                                             cnt, M, E);

    // 3) exclusive scan -> ptr, fill
    scan_rowptr<<<1, 1024, 0, stream>>>(cnt, ptr, fill, M);

    // 4) place edges (fill doubles as running insert cursor)
    build_sorted<<<(E + 255) / 256, 256, 0, stream>>>(edge_vals, edge_row, edge_col,
                                                      fill, edges, E);

    // 5) aggregate
    spmm_rows<<<(M + 3) / 4, 256, 0, stream>>>(S, edges, ptr, bias, out, M);
}